// Round 13
// baseline (108.644 us; speedup 1.0000x reference)
//
#include <hip/hip_runtime.h>
#include <stdint.h>

#define NMID  62
#define NPAIR 31
#define NBATCH 16384
#define BT    32          // batches per block (2 blocks/CU)

typedef __attribute__((ext_vector_type(8))) _Float16 half8;
typedef __attribute__((ext_vector_type(4))) float f32x4;
typedef __attribute__((ext_vector_type(4))) unsigned int u32x4;
typedef __attribute__((ext_vector_type(2))) unsigned int u32x2;

__device__ __forceinline__ unsigned short f16_bits(float f) {
    _Float16 h = (_Float16)f;              // v_cvt_f16_f32, RNE
    return __builtin_bit_cast(unsigned short, h);
}

// Bond schedule r_k, k = 0..61: 4,8,16,32,64,128...128,64,32,16,8,4,2
__device__ __forceinline__ float g_scale(int k) {
    int rk = (k < 5) ? (4 << k) : ((k < 56) ? 128 : (64 >> (k - 56)));
    return 16.0f * rsqrtf((float)rk);
}

// ---- pack: W2[p][l][i1][i2][r] = sum_m W[2p][l][i1][m] * W[2p+1][m][i2][r],
// f16, emitted DIRECTLY in main-kernel fragment order:
// u32x4 frag addr f = (((p*4 + i12)*8 + tr)*4 + kt)*64 + (agf*16 + arow);
// frag lane holds W2[l = kt*32 + agf*8 + j][i12][r = tr*16 + arow], j=0..7.
// Grid: 992 blocks = (p, i12, tr); 256 thr = 4 waves; wave wv owns tl = wv*2+{0,1}.
// B-slice staged in LDS (coalesced) -> same f32 values, same casts, same MFMA
// order as R10-R12 -> bit-identical W2.
__global__ __launch_bounds__(256) void mps_pack_w2(
    const float* __restrict__ wm, unsigned* __restrict__ wpk)
{
    __shared__ float Bs[128][16];          // 8 KB B-slice [m][rr]
    const int tr  = blockIdx.x & 7;
    const int i12 = (blockIdx.x >> 3) & 3;
    const int p   = blockIdx.x >> 5;
    const int i1 = i12 >> 1, i2 = i12 & 1;
    const int tid = threadIdx.x, lane = tid & 63, wv = tid >> 6;
    const int arow = lane & 15, ag = lane >> 4;
    const float* A  = wm + ((size_t)(2 * p) * 128) * 256 + i1 * 128;     // A[l*256 + m]
    const float* Bm = wm + ((size_t)(2 * p + 1) * 128) * 256 + i2 * 128; // B[m*256 + r]

    for (int idx = tid; idx < 128 * 16; idx += 256) {
        int m = idx >> 4, rr = idx & 15;
        Bs[m][rr] = Bm[(size_t)m * 256 + tr * 16 + rr];
    }
    __syncthreads();

    half8 bf[4];
    #pragma unroll
    for (int mk = 0; mk < 4; ++mk) {
        half8 h;
        #pragma unroll
        for (int j = 0; j < 8; ++j)
            h[j] = (_Float16)Bs[mk * 32 + ag * 8 + j][arow];
        bf[mk] = h;
    }
    #pragma unroll
    for (int tll = 0; tll < 2; ++tll) {
        const int tl = wv * 2 + tll;
        f32x4 acc = f32x4{0.f, 0.f, 0.f, 0.f};
        #pragma unroll
        for (int mk = 0; mk < 4; ++mk) {
            const float* ap = A + (size_t)(tl * 16 + arow) * 256 + mk * 32 + ag * 8;
            float4 a0 = *reinterpret_cast<const float4*>(ap);
            float4 a1 = *reinterpret_cast<const float4*>(ap + 4);
            half8 ah;
            ah[0] = (_Float16)a0.x; ah[1] = (_Float16)a0.y;
            ah[2] = (_Float16)a0.z; ah[3] = (_Float16)a0.w;
            ah[4] = (_Float16)a1.x; ah[5] = (_Float16)a1.y;
            ah[6] = (_Float16)a1.z; ah[7] = (_Float16)a1.w;
            acc = __builtin_amdgcn_mfma_f32_16x16x32_f16(ah, bf[mk], acc, 0, 0, 0);
        }
        const int l0 = tl * 16 + ag * 4;
        const int kt = l0 >> 5;
        const int o = l0 & 31;
        const int agf = o >> 3;
        const int d0 = (o & 7) >> 1;          // 0 or 2
        unsigned w0 = (unsigned)f16_bits(acc[0]) | ((unsigned)f16_bits(acc[1]) << 16);
        unsigned w1 = (unsigned)f16_bits(acc[2]) | ((unsigned)f16_bits(acc[3]) << 16);
        size_t dw = ((((size_t)(p * 4 + i12) * 8 + tr) * 4 + kt) * 64
                     + (agf * 16 + arow)) * 4 + d0;
        *reinterpret_cast<u32x2*>(wpk + dw) = u32x2{w0, w1};
    }
}

// ---- one fused pair step (BT=32): acc[bt][i12] = W2^T(frag A) x v^T(frag B);
// vn = sum_i12 P[i12]*acc[i12]; P precomputed in LDS. W single-buffered in regs
// (loads at pair top; 4 waves/SIMD cover the L2 latency). Per-element MFMA and
// epilogue order identical to R10-R12 -> bitwise-identical output.
__device__ __forceinline__ void do_pair(
    int p, const float* __restrict__ Pt, int lane, int rt,
    const unsigned short* __restrict__ vcur, unsigned short* __restrict__ vnxt,
    const u32x4* __restrict__ wpk)
{
    const int arow = lane & 15, ag = lane >> 4;

    // this pair's 16 W fragments (L2-resident)
    u32x4 W[16];
    #pragma unroll
    for (int i12 = 0; i12 < 4; ++i12)
        #pragma unroll
        for (int kt = 0; kt < 4; ++kt)
            W[i12 * 4 + kt] =
                wpk[(((size_t)(p * 4 + i12) * 8 + rt) * 4 + kt) * 64 + lane];

    // per-batch multipliers (LDS broadcast)
    f32x4 Pv[2];
    #pragma unroll
    for (int bt = 0; bt < 2; ++bt)
        Pv[bt] = *reinterpret_cast<const f32x4*>(&Pt[(p * BT + bt * 16 + arow) * 4]);

    f32x4 acc[2][4];
    #pragma unroll
    for (int bt = 0; bt < 2; ++bt)
        #pragma unroll
        for (int i12 = 0; i12 < 4; ++i12)
            acc[bt][i12] = f32x4{0.f, 0.f, 0.f, 0.f};

    #pragma unroll
    for (int kt = 0; kt < 4; ++kt) {
        half8 vf[2];
        #pragma unroll
        for (int bt = 0; bt < 2; ++bt) {
            int row = bt * 16 + arow;
            int boff = (row * 256 + kt * 64 + ag * 16) ^ ((row & 7) << 4);
            vf[bt] = *reinterpret_cast<const half8*>(
                reinterpret_cast<const char*>(vcur) + boff);
        }
        #pragma unroll
        for (int bt = 0; bt < 2; ++bt)
            #pragma unroll
            for (int i12 = 0; i12 < 4; ++i12)
                acc[bt][i12] = __builtin_amdgcn_mfma_f32_16x16x32_f16(
                    __builtin_bit_cast(half8, W[i12 * 4 + kt]), vf[bt],
                    acc[bt][i12], 0, 0, 0);
    }

    // epilogue: vn = sum_i12 P[i12]*acc[i12], RNE f16, one b64 store per bt
    #pragma unroll
    for (int bt = 0; bt < 2; ++bt) {
        unsigned short h[4];
        #pragma unroll
        for (int q = 0; q < 4; ++q) {
            float vn = Pv[bt][0] * acc[bt][0][q] + Pv[bt][1] * acc[bt][1][q]
                     + Pv[bt][2] * acc[bt][2][q] + Pv[bt][3] * acc[bt][3][q];
            h[q] = f16_bits(vn);
        }
        int row = bt * 16 + arow;
        int byte = (row * 256 + (rt * 16 + ag * 4) * 2) ^ ((row & 7) << 4);
        u32x2 pk;
        pk[0] = (unsigned)h[0] | ((unsigned)h[1] << 16);
        pk[1] = (unsigned)h[2] | ((unsigned)h[3] << 16);
        *reinterpret_cast<u32x2*>(reinterpret_cast<char*>(vnxt) + byte) = pk;
    }
    __syncthreads();
}

// ---- main: 512 blocks x 512 thr (8 waves = 8 r-tiles). Block = 32 batches,
// 2 blocks/CU (4 waves/SIMD): the co-resident block's MFMA phase overlaps this
// block's epilogue/barrier phase (the ~3000-cyc lockstep overhead).
__global__ __launch_bounds__(512, 4) void mps_mfma(
    const float* __restrict__ x, const float* __restrict__ wf,
    const float* __restrict__ wl, const u32x4* __restrict__ wpk,
    float* __restrict__ out)
{
    __shared__ unsigned short vh0[BT * 128];     // 8 KB ping
    __shared__ unsigned short vh1[BT * 128];     // 8 KB pong
    __shared__ float Pt[NPAIR * BT * 4];         // 15.875 KB pair multipliers
    const int tid = threadIdx.x;
    const int lane = tid & 63;
    const int rt = tid >> 6;
    const int bbase = blockIdx.x * BT;

    // prologue A: P[p][row][i12] = s * x_{2p,i1} * x_{2p+1,i2}
    for (int idx = tid; idx < NPAIR * BT; idx += 512) {
        int pp = idx / BT, row = idx % BT;
        const float* xb = &x[(size_t)(bbase + row) * 128 + 2 + 4 * pp];
        float2 xa = *reinterpret_cast<const float2*>(xb);
        float2 xc = *reinterpret_cast<const float2*>(xb + 2);
        float n2a = fmaf(xa.x, xa.x, fmaf(xa.y, xa.y, 1e-30f));
        float n2b = fmaf(xc.x, xc.x, fmaf(xc.y, xc.y, 1e-30f));
        float s = g_scale(2 * pp) * rsqrtf(n2a) * g_scale(2 * pp + 1) * rsqrtf(n2b);
        Pt[idx * 4 + 0] = s * xa.x * xc.x;
        Pt[idx * 4 + 1] = s * xa.x * xc.y;
        Pt[idx * 4 + 2] = s * xa.y * xc.x;
        Pt[idx * 4 + 3] = s * xa.y * xc.y;
    }

    // prologue B: v0 (only l<2 nonzero), normalized by s_init = 8*rsqrt(|x_0|^2)
    const float wf00 = wf[0], wf01 = wf[1], wf10 = wf[2], wf11 = wf[3];
    for (int idx = tid; idx < BT * 128; idx += 512) {
        int row = idx >> 7, l = idx & 127;
        float val = 0.f;
        if (l < 2) {
            float x0 = x[(size_t)(bbase + row) * 128 + 0];
            float x1 = x[(size_t)(bbase + row) * 128 + 1];
            float n2 = fmaf(x0, x0, fmaf(x1, x1, 1e-30f));
            float si = 8.0f * rsqrtf(n2);
            val = si * ((l == 0) ? (wf00 * x0 + wf10 * x1) : (wf01 * x0 + wf11 * x1));
        }
        int byte = (row * 256 + l * 2) ^ ((row & 7) << 4);
        *reinterpret_cast<unsigned short*>(
            reinterpret_cast<char*>(vh0) + byte) = f16_bits(val);
    }
    __syncthreads();

    // pair loop: 31 pairs, ping-pong (unrolled by 2 for static buffer naming)
    for (int p = 0; p < 30; p += 2) {
        do_pair(p,     Pt, lane, rt, vh0, vh1, wpk);
        do_pair(p + 1, Pt, lane, rt, vh1, vh0, wpk);
    }
    do_pair(30, Pt, lane, rt, vh0, vh1, wpk);

    // finale: recompute alpha from global x (same factors as applied in-chain)
    if (tid < BT) {
        int row = tid;
        const float* xb = &x[(size_t)(bbase + row) * 128];
        float n2i = fmaf(xb[0], xb[0], fmaf(xb[1], xb[1], 1e-30f));
        float alpha = 8.0f * rsqrtf(n2i);
        for (int k = 0; k < NMID; ++k) {
            float2 xx = *reinterpret_cast<const float2*>(&xb[2 + 2 * k]);
            float n2 = fmaf(xx.x, xx.x, fmaf(xx.y, xx.y, 1e-30f));
            alpha *= g_scale(k) * rsqrtf(n2);
        }
        int boff = (row * 256) ^ ((row & 7) << 4);
        unsigned hw = *reinterpret_cast<unsigned*>(
            reinterpret_cast<char*>(vh1) + boff);
        float v0 = (float)__builtin_bit_cast(_Float16, (unsigned short)(hw & 0xffffu));
        float v1 = (float)__builtin_bit_cast(_Float16, (unsigned short)(hw >> 16));
        float x0 = xb[126], x1 = xb[127];
        float val = v0 * (wl[0] * x0 + wl[1] * x1)
                  + v1 * (wl[2] * x0 + wl[3] * x1);
        out[bbase + row] = val / alpha;
    }
}

// ---------------- fallback fp32 vector kernel (used only if ws too small) ----
#define FBT 32
__global__ __launch_bounds__(256, 2) void mps_chain_kernel(
    const float* __restrict__ x, const float* __restrict__ wf,
    const float* __restrict__ wm, const float* __restrict__ wl,
    float* __restrict__ out)
{
    __shared__ float vbuf[2][128][FBT];
    __shared__ float xs_lds[FBT][126];
    const int tid = threadIdx.x;
    const int rg = tid >> 3, bg = tid & 7;
    const int r0 = rg * 4, b0 = bg * 4;
    const int bbase = blockIdx.x * FBT;
    for (int idx = tid; idx < FBT * 126; idx += 256) {
        int b = idx / 126, j = idx % 126;
        xs_lds[b][j] = x[(size_t)(bbase + b) * 128 + 2 + j];
    }
    const float wf00 = wf[0], wf01 = wf[1], wf10 = wf[2], wf11 = wf[3];
    for (int idx = tid; idx < 128 * FBT; idx += 256) {
        int l = idx / FBT, b = idx % FBT;
        float val = 0.0f;
        if (l < 2) {
            float x0 = x[(size_t)(bbase + b) * 128 + 0];
            float x1 = x[(size_t)(bbase + b) * 128 + 1];
            val = (l == 0) ? (wf00 * x0 + wf10 * x1) : (wf01 * x0 + wf11 * x1);
        }
        vbuf[0][l][b] = val;
    }
    __syncthreads();
    int cur = 0;
    for (int k = 0; k < NMID; ++k) {
        const float* __restrict__ Wk = wm + (size_t)k * (2 * 128 * 128);
        float acc0[4][4], acc1[4][4];
        #pragma unroll
        for (int bb = 0; bb < 4; ++bb)
            #pragma unroll
            for (int rr = 0; rr < 4; ++rr) { acc0[bb][rr] = 0.0f; acc1[bb][rr] = 0.0f; }
        #pragma unroll 4
        for (int l = 0; l < 128; ++l) {
            float4 vv = *reinterpret_cast<const float4*>(&vbuf[cur][l][b0]);
            float4 w0 = *reinterpret_cast<const float4*>(&Wk[(size_t)(2 * l) * 128 + r0]);
            float4 w1 = *reinterpret_cast<const float4*>(&Wk[(size_t)(2 * l + 1) * 128 + r0]);
            float va[4] = { vv.x, vv.y, vv.z, vv.w };
            float w0a[4] = { w0.x, w0.y, w0.z, w0.w };
            float w1a[4] = { w1.x, w1.y, w1.z, w1.w };
            #pragma unroll
            for (int bb = 0; bb < 4; ++bb)
                #pragma unroll
                for (int rr = 0; rr < 4; ++rr) {
                    acc0[bb][rr] = fmaf(va[bb], w0a[rr], acc0[bb][rr]);
                    acc1[bb][rr] = fmaf(va[bb], w1a[rr], acc1[bb][rr]);
                }
        }
        const int nxt = cur ^ 1;
        float vn[4][4];
        #pragma unroll
        for (int bb = 0; bb < 4; ++bb) {
            float xx0 = xs_lds[b0 + bb][2 * k + 0];
            float xx1 = xs_lds[b0 + bb][2 * k + 1];
            #pragma unroll
            for (int rr = 0; rr < 4; ++rr)
                vn[bb][rr] = xx0 * acc0[bb][rr] + xx1 * acc1[bb][rr];
        }
        #pragma unroll
        for (int rr = 0; rr < 4; ++rr) {
            float4 wv = make_float4(vn[0][rr], vn[1][rr], vn[2][rr], vn[3][rr]);
            *reinterpret_cast<float4*>(&vbuf[nxt][r0 + rr][b0]) = wv;
        }
        cur = nxt;
        __syncthreads();
    }
    if (rg == 0) {
        const float wl00 = wl[0], wl01 = wl[1], wl10 = wl[2], wl11 = wl[3];
        #pragma unroll
        for (int bb = 0; bb < 4; ++bb) {
            int b = b0 + bb;
            float v0 = vbuf[cur][0][b];
            float v1 = vbuf[cur][1][b];
            float xx0 = xs_lds[b][124];
            float xx1 = xs_lds[b][125];
            out[bbase + b] = v0 * (wl00 * xx0 + wl01 * xx1)
                           + v1 * (wl10 * xx0 + wl11 * xx1);
        }
    }
}

extern "C" void kernel_launch(void* const* d_in, const int* in_sizes, int n_in,
                              void* d_out, int out_size, void* d_ws, size_t ws_size,
                              hipStream_t stream) {
    const float* x  = (const float*)d_in[0];
    const float* wf = (const float*)d_in[1];
    const float* wm = (const float*)d_in[2];
    const float* wl = (const float*)d_in[3];
    float* out = (float*)d_out;

    const size_t ws_needed = (size_t)NPAIR * 4 * 8 * 4 * 64 * 16;  // 4.06 MB packed W2
    if (ws_size >= ws_needed) {
        hipLaunchKernelGGL(mps_pack_w2, dim3(NPAIR * 4 * 8), dim3(256), 0, stream,
                           wm, (unsigned*)d_ws);
        hipLaunchKernelGGL(mps_mfma, dim3(NBATCH / BT), dim3(512), 0, stream,
                           x, wf, wl, (const u32x4*)d_ws, out);
    } else {
        hipLaunchKernelGGL(mps_chain_kernel, dim3(NBATCH / FBT), dim3(256), 0, stream,
                           x, wf, wm, wl, out);
    }
}

// Round 15
// 88.156 us; speedup vs baseline: 1.2324x; 1.2324x over previous
//
#include <hip/hip_runtime.h>
#include <stdint.h>

#define NMID  62
#define NPAIR 31
#define NBATCH 16384
#define BT    64          // batches per block (1 block/CU)

typedef __attribute__((ext_vector_type(8))) _Float16 half8;
typedef __attribute__((ext_vector_type(4))) float f32x4;
typedef __attribute__((ext_vector_type(4))) unsigned int u32x4;
typedef __attribute__((ext_vector_type(2))) unsigned int u32x2;

__device__ __forceinline__ unsigned short f16_bits(float f) {
    _Float16 h = (_Float16)f;              // v_cvt_f16_f32, RNE
    return __builtin_bit_cast(unsigned short, h);
}

// Bond schedule r_k, k = 0..61: 4,8,16,32,64,128...128,64,32,16,8,4,2
__device__ __forceinline__ float g_scale(int k) {
    int rk = (k < 5) ? (4 << k) : ((k < 56) ? 128 : (64 >> (k - 56)));
    return 16.0f * rsqrtf((float)rk);
}

// ---- pack: W2[p][l][i1][i2][r] = sum_m W[2p][l][i1][m] * W[2p+1][m][i2][r],
// f16, emitted DIRECTLY in main-kernel fragment order (bit-identical to R10-R13).
__global__ __launch_bounds__(256) void mps_pack_w2(
    const float* __restrict__ wm, unsigned* __restrict__ wpk)
{
    __shared__ float Bs[128][16];          // 8 KB B-slice [m][rr]
    const int tr  = blockIdx.x & 7;
    const int i12 = (blockIdx.x >> 3) & 3;
    const int p   = blockIdx.x >> 5;
    const int i1 = i12 >> 1, i2 = i12 & 1;
    const int tid = threadIdx.x, lane = tid & 63, wv = tid >> 6;
    const int arow = lane & 15, ag = lane >> 4;
    const float* A  = wm + ((size_t)(2 * p) * 128) * 256 + i1 * 128;     // A[l*256 + m]
    const float* Bm = wm + ((size_t)(2 * p + 1) * 128) * 256 + i2 * 128; // B[m*256 + r]

    for (int idx = tid; idx < 128 * 16; idx += 256) {
        int m = idx >> 4, rr = idx & 15;
        Bs[m][rr] = Bm[(size_t)m * 256 + tr * 16 + rr];
    }
    __syncthreads();

    half8 bf[4];
    #pragma unroll
    for (int mk = 0; mk < 4; ++mk) {
        half8 h;
        #pragma unroll
        for (int j = 0; j < 8; ++j)
            h[j] = (_Float16)Bs[mk * 32 + ag * 8 + j][arow];
        bf[mk] = h;
    }
    #pragma unroll
    for (int tll = 0; tll < 2; ++tll) {
        const int tl = wv * 2 + tll;
        f32x4 acc = f32x4{0.f, 0.f, 0.f, 0.f};
        #pragma unroll
        for (int mk = 0; mk < 4; ++mk) {
            const float* ap = A + (size_t)(tl * 16 + arow) * 256 + mk * 32 + ag * 8;
            float4 a0 = *reinterpret_cast<const float4*>(ap);
            float4 a1 = *reinterpret_cast<const float4*>(ap + 4);
            half8 ah;
            ah[0] = (_Float16)a0.x; ah[1] = (_Float16)a0.y;
            ah[2] = (_Float16)a0.z; ah[3] = (_Float16)a0.w;
            ah[4] = (_Float16)a1.x; ah[5] = (_Float16)a1.y;
            ah[6] = (_Float16)a1.z; ah[7] = (_Float16)a1.w;
            acc = __builtin_amdgcn_mfma_f32_16x16x32_f16(ah, bf[mk], acc, 0, 0, 0);
        }
        const int l0 = tl * 16 + ag * 4;
        const int kt = l0 >> 5;
        const int o = l0 & 31;
        const int agf = o >> 3;
        const int d0 = (o & 7) >> 1;          // 0 or 2
        unsigned w0 = (unsigned)f16_bits(acc[0]) | ((unsigned)f16_bits(acc[1]) << 16);
        unsigned w1 = (unsigned)f16_bits(acc[2]) | ((unsigned)f16_bits(acc[3]) << 16);
        size_t dw = ((((size_t)(p * 4 + i12) * 8 + tr) * 4 + kt) * 64
                     + (agf * 16 + arow)) * 4 + d0;
        *reinterpret_cast<u32x2*>(wpk + dw) = u32x2{w0, w1};
    }
}

// ---- main-kernel helpers: vf read (4 x ds_read_b128) and 16-MFMA cluster ----
__device__ __forceinline__ void rd_vf(const unsigned short* __restrict__ vcur,
                                      int kt, int arow, int ag, half8 (&vf)[4]) {
    #pragma unroll
    for (int bt = 0; bt < 4; ++bt) {
        int row = bt * 16 + arow;
        int boff = (row * 256 + kt * 64 + ag * 16) ^ ((row & 7) << 4);
        vf[bt] = *reinterpret_cast<const half8*>(
            reinterpret_cast<const char*>(vcur) + boff);
    }
}
__device__ __forceinline__ void mm_kt(f32x4 (&acc)[4][4], const u32x4 (&W)[16],
                                      const half8 (&vf)[4], int kt) {
    #pragma unroll
    for (int bt = 0; bt < 4; ++bt)
        #pragma unroll
        for (int i12 = 0; i12 < 4; ++i12)
            acc[bt][i12] = __builtin_amdgcn_mfma_f32_16x16x32_f16(
                __builtin_bit_cast(half8, W[i12 * 4 + kt]), vf[bt],
                acc[bt][i12], 0, 0, 0);
}

// ---- one fused pair step: acc[bt][i12] = W2^T(frag A) x v^T(frag B);
// vn = sum_i12 P[i12]*acc[i12]. Identical arithmetic to R10-R12.
// ONLY change vs R12: the in-loop barrier waits lgkmcnt(0) ONLY — the LDS
// ping-pong is the sole cross-wave dependency. W loads are compiler-managed
// (correct counted vmcnt before each use) and now stay in flight ACROSS the
// barrier instead of being drained by __syncthreads' vmcnt(0).
__device__ __forceinline__ void do_pair(
    int p, const float* __restrict__ Pt, int lane, int rt,
    const unsigned short* __restrict__ vcur, unsigned short* __restrict__ vnxt,
    const u32x4* __restrict__ wpk, int pnext,
    u32x4 (&Wcur)[16], u32x4 (&Wnxt)[16])
{
    const int arow = lane & 15, ag = lane >> 4;

    // pin this pair's W regs read-write: forces completion here (their loads
    // were issued one full pair ago -> ~free) and blocks rematerialization.
    #pragma unroll
    for (int j = 0; j < 16; ++j)
        asm volatile("" : "+v"(Wcur[j]));

    // issue next pair's 16 fragment loads (L2-resident); not waited this pair
    #pragma unroll
    for (int i12 = 0; i12 < 4; ++i12)
        #pragma unroll
        for (int kt = 0; kt < 4; ++kt)
            Wnxt[i12 * 4 + kt] =
                wpk[(((size_t)(pnext * 4 + i12) * 8 + rt) * 4 + kt) * 64 + lane];

    // per-batch multipliers (LDS broadcast)
    f32x4 Pv[4];
    #pragma unroll
    for (int bt = 0; bt < 4; ++bt)
        Pv[bt] = *reinterpret_cast<const f32x4*>(&Pt[(p * 64 + bt * 16 + arow) * 4]);

    f32x4 acc[4][4];
    #pragma unroll
    for (int bt = 0; bt < 4; ++bt)
        #pragma unroll
        for (int i12 = 0; i12 < 4; ++i12)
            acc[bt][i12] = f32x4{0.f, 0.f, 0.f, 0.f};

    // pipelined kt loop (same MFMA order per acc -> numerics identical)
    half8 v0[4], v1[4];
    rd_vf(vcur, 0, arow, ag, v0);
    rd_vf(vcur, 1, arow, ag, v1);
    mm_kt(acc, Wcur, v0, 0);
    rd_vf(vcur, 2, arow, ag, v0);
    mm_kt(acc, Wcur, v1, 1);
    rd_vf(vcur, 3, arow, ag, v1);
    mm_kt(acc, Wcur, v0, 2);
    mm_kt(acc, Wcur, v1, 3);

    // epilogue: vn = sum_i12 P[i12]*acc[i12], RNE f16, one b64 store per bt
    #pragma unroll
    for (int bt = 0; bt < 4; ++bt) {
        unsigned short h[4];
        #pragma unroll
        for (int q = 0; q < 4; ++q) {
            float vn = Pv[bt][0] * acc[bt][0][q] + Pv[bt][1] * acc[bt][1][q]
                     + Pv[bt][2] * acc[bt][2][q] + Pv[bt][3] * acc[bt][3][q];
            h[q] = f16_bits(vn);
        }
        int row = bt * 16 + arow;
        int byte = (row * 256 + (rt * 16 + ag * 4) * 2) ^ ((row & 7) << 4);
        u32x2 pk;
        pk[0] = (unsigned)h[0] | ((unsigned)h[1] << 16);
        pk[1] = (unsigned)h[2] | ((unsigned)h[3] << 16);
        *reinterpret_cast<u32x2*>(reinterpret_cast<char*>(vnxt) + byte) = pk;
    }

    // lgkm-only barrier: LDS writes drained; W vmem stream NOT drained.
    asm volatile("s_waitcnt lgkmcnt(0)\n\ts_barrier" ::: "memory");
}

// ---- main: 256 blocks x 512 thr (8 waves = 8 r-tiles). Block = 64 batches,
// 1 block/CU (minimum W L2 traffic per CU: 128 KB/pair).
__global__ __launch_bounds__(512, 2) void mps_mfma(
    const float* __restrict__ x, const float* __restrict__ wf,
    const float* __restrict__ wl, const u32x4* __restrict__ wpk,
    float* __restrict__ out)
{
    __shared__ unsigned short vh0[BT * 128];     // 16 KB ping
    __shared__ unsigned short vh1[BT * 128];     // 16 KB pong
    __shared__ float Pt[NPAIR * BT * 4];         // 31.75 KB pair multipliers
    const int tid = threadIdx.x;
    const int lane = tid & 63;
    const int rt = tid >> 6;
    const int bbase = blockIdx.x * BT;

    // prologue A: P[p][row][i12] = s * x_{2p,i1} * x_{2p+1,i2}
    for (int idx = tid; idx < NPAIR * BT; idx += 512) {
        int pp = idx >> 6, row = idx & 63;
        const float* xb = &x[(size_t)(bbase + row) * 128 + 2 + 4 * pp];
        float2 xa = *reinterpret_cast<const float2*>(xb);
        float2 xc = *reinterpret_cast<const float2*>(xb + 2);
        float n2a = fmaf(xa.x, xa.x, fmaf(xa.y, xa.y, 1e-30f));
        float n2b = fmaf(xc.x, xc.x, fmaf(xc.y, xc.y, 1e-30f));
        float s = g_scale(2 * pp) * rsqrtf(n2a) * g_scale(2 * pp + 1) * rsqrtf(n2b);
        Pt[idx * 4 + 0] = s * xa.x * xc.x;
        Pt[idx * 4 + 1] = s * xa.x * xc.y;
        Pt[idx * 4 + 2] = s * xa.y * xc.x;
        Pt[idx * 4 + 3] = s * xa.y * xc.y;
    }

    // prologue B: v0 (only l<2 nonzero), normalized by s_init = 8*rsqrt(|x_0|^2)
    const float wf00 = wf[0], wf01 = wf[1], wf10 = wf[2], wf11 = wf[3];
    for (int idx = tid; idx < BT * 128; idx += 512) {
        int row = idx >> 7, l = idx & 127;
        float val = 0.f;
        if (l < 2) {
            float x0 = x[(size_t)(bbase + row) * 128 + 0];
            float x1 = x[(size_t)(bbase + row) * 128 + 1];
            float n2 = fmaf(x0, x0, fmaf(x1, x1, 1e-30f));
            float si = 8.0f * rsqrtf(n2);
            val = si * ((l == 0) ? (wf00 * x0 + wf10 * x1) : (wf01 * x0 + wf11 * x1));
        }
        int byte = (row * 256 + l * 2) ^ ((row & 7) << 4);
        *reinterpret_cast<unsigned short*>(
            reinterpret_cast<char*>(vh0) + byte) = f16_bits(val);
    }
    __syncthreads();

    // pair loop: 31 pairs, unrolled by 2 with named W double-buffer
    u32x4 WA[16], WB[16];
    #pragma unroll
    for (int i12 = 0; i12 < 4; ++i12)
        #pragma unroll
        for (int kt = 0; kt < 4; ++kt)
            WA[i12 * 4 + kt] = wpk[(((size_t)i12 * 8 + rt) * 4 + kt) * 64 + lane];

    for (int p = 0; p < 30; p += 2) {
        do_pair(p,     Pt, lane, rt, vh0, vh1, wpk, p + 1, WA, WB);
        do_pair(p + 1, Pt, lane, rt, vh1, vh0, wpk, p + 2, WB, WA);
    }
    do_pair(30, Pt, lane, rt, vh0, vh1, wpk, 30, WA, WB);  // dummy prefetch

    // finale: recompute alpha from global x (same factors as applied in-chain)
    if (tid < BT) {
        int row = tid;
        const float* xb = &x[(size_t)(bbase + row) * 128];
        float n2i = fmaf(xb[0], xb[0], fmaf(xb[1], xb[1], 1e-30f));
        float alpha = 8.0f * rsqrtf(n2i);
        for (int k = 0; k < NMID; ++k) {
            float2 xx = *reinterpret_cast<const float2*>(&xb[2 + 2 * k]);
            float n2 = fmaf(xx.x, xx.x, fmaf(xx.y, xx.y, 1e-30f));
            alpha *= g_scale(k) * rsqrtf(n2);
        }
        int boff = (row * 256) ^ ((row & 7) << 4);
        unsigned hw = *reinterpret_cast<unsigned*>(
            reinterpret_cast<char*>(vh1) + boff);
        float v0 = (float)__builtin_bit_cast(_Float16, (unsigned short)(hw & 0xffffu));
        float v1 = (float)__builtin_bit_cast(_Float16, (unsigned short)(hw >> 16));
        float x0 = xb[126], x1 = xb[127];
        float val = v0 * (wl[0] * x0 + wl[1] * x1)
                  + v1 * (wl[2] * x0 + wl[3] * x1);
        out[bbase + row] = val / alpha;
    }
}

// ---------------- fallback fp32 vector kernel (used only if ws too small) ----
#define FBT 32
__global__ __launch_bounds__(256, 2) void mps_chain_kernel(
    const float* __restrict__ x, const float* __restrict__ wf,
    const float* __restrict__ wm, const float* __restrict__ wl,
    float* __restrict__ out)
{
    __shared__ float vbuf[2][128][FBT];
    __shared__ float xs_lds[FBT][126];
    const int tid = threadIdx.x;
    const int rg = tid >> 3, bg = tid & 7;
    const int r0 = rg * 4, b0 = bg * 4;
    const int bbase = blockIdx.x * FBT;
    for (int idx = tid; idx < FBT * 126; idx += 256) {
        int b = idx / 126, j = idx % 126;
        xs_lds[b][j] = x[(size_t)(bbase + b) * 128 + 2 + j];
    }
    const float wf00 = wf[0], wf01 = wf[1], wf10 = wf[2], wf11 = wf[3];
    for (int idx = tid; idx < 128 * FBT; idx += 256) {
        int l = idx / FBT, b = idx % FBT;
        float val = 0.0f;
        if (l < 2) {
            float x0 = x[(size_t)(bbase + b) * 128 + 0];
            float x1 = x[(size_t)(bbase + b) * 128 + 1];
            val = (l == 0) ? (wf00 * x0 + wf10 * x1) : (wf01 * x0 + wf11 * x1);
        }
        vbuf[0][l][b] = val;
    }
    __syncthreads();
    int cur = 0;
    for (int k = 0; k < NMID; ++k) {
        const float* __restrict__ Wk = wm + (size_t)k * (2 * 128 * 128);
        float acc0[4][4], acc1[4][4];
        #pragma unroll
        for (int bb = 0; bb < 4; ++bb)
            #pragma unroll
            for (int rr = 0; rr < 4; ++rr) { acc0[bb][rr] = 0.0f; acc1[bb][rr] = 0.0f; }
        #pragma unroll 4
        for (int l = 0; l < 128; ++l) {
            float4 vv = *reinterpret_cast<const float4*>(&vbuf[cur][l][b0]);
            float4 w0 = *reinterpret_cast<const float4*>(&Wk[(size_t)(2 * l) * 128 + r0]);
            float4 w1 = *reinterpret_cast<const float4*>(&Wk[(size_t)(2 * l + 1) * 128 + r0]);
            float va[4] = { vv.x, vv.y, vv.z, vv.w };
            float w0a[4] = { w0.x, w0.y, w0.z, w0.w };
            float w1a[4] = { w1.x, w1.y, w1.z, w1.w };
            #pragma unroll
            for (int bb = 0; bb < 4; ++bb)
                #pragma unroll
                for (int rr = 0; rr < 4; ++rr) {
                    acc0[bb][rr] = fmaf(va[bb], w0a[rr], acc0[bb][rr]);
                    acc1[bb][rr] = fmaf(va[bb], w1a[rr], acc1[bb][rr]);
                }
        }
        const int nxt = cur ^ 1;
        float vn[4][4];
        #pragma unroll
        for (int bb = 0; bb < 4; ++bb) {
            float xx0 = xs_lds[b0 + bb][2 * k + 0];
            float xx1 = xs_lds[b0 + bb][2 * k + 1];
            #pragma unroll
            for (int rr = 0; rr < 4; ++rr)
                vn[bb][rr] = xx0 * acc0[bb][rr] + xx1 * acc1[bb][rr];
        }
        #pragma unroll
        for (int rr = 0; rr < 4; ++rr) {
            float4 wv = make_float4(vn[0][rr], vn[1][rr], vn[2][rr], vn[3][rr]);
            *reinterpret_cast<float4*>(&vbuf[nxt][r0 + rr][b0]) = wv;
        }
        cur = nxt;
        __syncthreads();
    }
    if (rg == 0) {
        const float wl00 = wl[0], wl01 = wl[1], wl10 = wl[2], wl11 = wl[3];
        #pragma unroll
        for (int bb = 0; bb < 4; ++bb) {
            int b = b0 + bb;
            float v0 = vbuf[cur][0][b];
            float v1 = vbuf[cur][1][b];
            float xx0 = xs_lds[b][124];
            float xx1 = xs_lds[b][125];
            out[bbase + b] = v0 * (wl00 * xx0 + wl01 * xx1)
                           + v1 * (wl10 * xx0 + wl11 * xx1);
        }
    }
}

extern "C" void kernel_launch(void* const* d_in, const int* in_sizes, int n_in,
                              void* d_out, int out_size, void* d_ws, size_t ws_size,
                              hipStream_t stream) {
    const float* x  = (const float*)d_in[0];
    const float* wf = (const float*)d_in[1];
    const float* wm = (const float*)d_in[2];
    const float* wl = (const float*)d_in[3];
    float* out = (float*)d_out;

    const size_t ws_needed = (size_t)NPAIR * 4 * 8 * 4 * 64 * 16;  // 4.06 MB packed W2
    if (ws_size >= ws_needed) {
        hipLaunchKernelGGL(mps_pack_w2, dim3(NPAIR * 4 * 8), dim3(256), 0, stream,
                           wm, (unsigned*)d_ws);
        hipLaunchKernelGGL(mps_mfma, dim3(NBATCH / BT), dim3(512), 0, stream,
                           x, wf, wl, (const u32x4*)d_ws, out);
    } else {
        hipLaunchKernelGGL(mps_chain_kernel, dim3(NBATCH / FBT), dim3(256), 0, stream,
                           x, wf, wm, wl, out);
    }
}

// Round 16
// 81.406 us; speedup vs baseline: 1.3346x; 1.0829x over previous
//
#include <hip/hip_runtime.h>
#include <stdint.h>

#define NMID  62
#define NPAIR 31
#define NBATCH 16384
#define BT    64          // batches per block (1 block/CU)

typedef __attribute__((ext_vector_type(8))) _Float16 half8;
typedef __attribute__((ext_vector_type(4))) float f32x4;
typedef __attribute__((ext_vector_type(4))) unsigned int u32x4;
typedef __attribute__((ext_vector_type(2))) unsigned int u32x2;

__device__ __forceinline__ unsigned short f16_bits(float f) {
    _Float16 h = (_Float16)f;              // v_cvt_f16_f32, RNE
    return __builtin_bit_cast(unsigned short, h);
}

// Bond schedule r_k, k = 0..61: 4,8,16,32,64,128...128,64,32,16,8,4,2
__device__ __forceinline__ float g_scale(int k) {
    int rk = (k < 5) ? (4 << k) : ((k < 56) ? 128 : (64 >> (k - 56)));
    return 16.0f * rsqrtf((float)rk);
}

// ---- pack: W2[p][l][i1][i2][r] = sum_m W[2p][l][i1][m] * W[2p+1][m][i2][r],
// f16, emitted DIRECTLY in main-kernel fragment order (bit-identical to R10-R15).
__global__ __launch_bounds__(256) void mps_pack_w2(
    const float* __restrict__ wm, unsigned* __restrict__ wpk)
{
    __shared__ float Bs[128][16];          // 8 KB B-slice [m][rr]
    const int tr  = blockIdx.x & 7;
    const int i12 = (blockIdx.x >> 3) & 3;
    const int p   = blockIdx.x >> 5;
    const int i1 = i12 >> 1, i2 = i12 & 1;
    const int tid = threadIdx.x, lane = tid & 63, wv = tid >> 6;
    const int arow = lane & 15, ag = lane >> 4;
    const float* A  = wm + ((size_t)(2 * p) * 128) * 256 + i1 * 128;     // A[l*256 + m]
    const float* Bm = wm + ((size_t)(2 * p + 1) * 128) * 256 + i2 * 128; // B[m*256 + r]

    for (int idx = tid; idx < 128 * 16; idx += 256) {
        int m = idx >> 4, rr = idx & 15;
        Bs[m][rr] = Bm[(size_t)m * 256 + tr * 16 + rr];
    }
    __syncthreads();

    half8 bf[4];
    #pragma unroll
    for (int mk = 0; mk < 4; ++mk) {
        half8 h;
        #pragma unroll
        for (int j = 0; j < 8; ++j)
            h[j] = (_Float16)Bs[mk * 32 + ag * 8 + j][arow];
        bf[mk] = h;
    }
    #pragma unroll
    for (int tll = 0; tll < 2; ++tll) {
        const int tl = wv * 2 + tll;
        f32x4 acc = f32x4{0.f, 0.f, 0.f, 0.f};
        #pragma unroll
        for (int mk = 0; mk < 4; ++mk) {
            const float* ap = A + (size_t)(tl * 16 + arow) * 256 + mk * 32 + ag * 8;
            float4 a0 = *reinterpret_cast<const float4*>(ap);
            float4 a1 = *reinterpret_cast<const float4*>(ap + 4);
            half8 ah;
            ah[0] = (_Float16)a0.x; ah[1] = (_Float16)a0.y;
            ah[2] = (_Float16)a0.z; ah[3] = (_Float16)a0.w;
            ah[4] = (_Float16)a1.x; ah[5] = (_Float16)a1.y;
            ah[6] = (_Float16)a1.z; ah[7] = (_Float16)a1.w;
            acc = __builtin_amdgcn_mfma_f32_16x16x32_f16(ah, bf[mk], acc, 0, 0, 0);
        }
        const int l0 = tl * 16 + ag * 4;
        const int kt = l0 >> 5;
        const int o = l0 & 31;
        const int agf = o >> 3;
        const int d0 = (o & 7) >> 1;          // 0 or 2
        unsigned w0 = (unsigned)f16_bits(acc[0]) | ((unsigned)f16_bits(acc[1]) << 16);
        unsigned w1 = (unsigned)f16_bits(acc[2]) | ((unsigned)f16_bits(acc[3]) << 16);
        size_t dw = ((((size_t)(p * 4 + i12) * 8 + tr) * 4 + kt) * 64
                     + (agf * 16 + arow)) * 4 + d0;
        *reinterpret_cast<u32x2*>(wpk + dw) = u32x2{w0, w1};
    }
}

// ---- main-kernel helpers: vf read (4 x ds_read_b128) and 16-MFMA cluster ----
__device__ __forceinline__ void rd_vf(const unsigned short* __restrict__ vcur,
                                      int kt, int arow, int ag, half8 (&vf)[4]) {
    #pragma unroll
    for (int bt = 0; bt < 4; ++bt) {
        int row = bt * 16 + arow;
        int boff = (row * 256 + kt * 64 + ag * 16) ^ ((row & 7) << 4);
        vf[bt] = *reinterpret_cast<const half8*>(
            reinterpret_cast<const char*>(vcur) + boff);
    }
}
__device__ __forceinline__ void mm_kt(f32x4 (&acc)[4][4], const u32x4 (&W)[16],
                                      const half8 (&vf)[4], int kt) {
    #pragma unroll
    for (int bt = 0; bt < 4; ++bt)
        #pragma unroll
        for (int i12 = 0; i12 < 4; ++i12)
            acc[bt][i12] = __builtin_amdgcn_mfma_f32_16x16x32_f16(
                __builtin_bit_cast(half8, W[i12 * 4 + kt]), vf[bt],
                acc[bt][i12], 0, 0, 0);
}

// ---- one fused pair, bond-schedule sparsity specialized.
// KTN: active l-tiles this pair (1 or 4). KTNN: active l-tiles of prefetched
// pair. act/actn: whether THIS wave's r-tile is active for p / pnext (wave-
// uniform). Inactive waves skip W loads + MFMA and store zeros (bitwise equal
// to the computed +0s, since the skipped W fragments are structurally zero).
template <int KTN, int KTNN>
__device__ __forceinline__ void do_pair(
    int p, int pnext, bool act, bool actn,
    const float* __restrict__ Pt, int lane, int rt,
    const unsigned short* __restrict__ vcur, unsigned short* __restrict__ vnxt,
    const u32x4* __restrict__ wpk,
    u32x4 (&Wcur)[16], u32x4 (&Wnxt)[16])
{
    const int arow = lane & 15, ag = lane >> 4;

    if (act) {
        // pin this pair's active W regs (loaded one full pair ago -> ~free),
        // blocking rematerialization at the consumption site.
        #pragma unroll
        for (int i12 = 0; i12 < 4; ++i12)
            #pragma unroll
            for (int kt = 0; kt < KTN; ++kt)
                asm volatile("" : "+v"(Wcur[i12 * 4 + kt]));
    }

    if (actn) {
        // issue next pair's active fragment loads; not waited in this pair
        #pragma unroll
        for (int i12 = 0; i12 < 4; ++i12)
            #pragma unroll
            for (int kt = 0; kt < KTNN; ++kt)
                Wnxt[i12 * 4 + kt] =
                    wpk[(((size_t)(pnext * 4 + i12) * 8 + rt) * 4 + kt) * 64 + lane];
    }

    if (act) {
        f32x4 Pv[4];
        #pragma unroll
        for (int bt = 0; bt < 4; ++bt)
            Pv[bt] = *reinterpret_cast<const f32x4*>(
                &Pt[(p * 64 + bt * 16 + arow) * 4]);

        f32x4 acc[4][4];
        #pragma unroll
        for (int bt = 0; bt < 4; ++bt)
            #pragma unroll
            for (int i12 = 0; i12 < 4; ++i12)
                acc[bt][i12] = f32x4{0.f, 0.f, 0.f, 0.f};

        if constexpr (KTN == 4) {
            half8 v0[4], v1[4];
            rd_vf(vcur, 0, arow, ag, v0);
            rd_vf(vcur, 1, arow, ag, v1);
            mm_kt(acc, Wcur, v0, 0);
            rd_vf(vcur, 2, arow, ag, v0);
            mm_kt(acc, Wcur, v1, 1);
            rd_vf(vcur, 3, arow, ag, v1);
            mm_kt(acc, Wcur, v0, 2);
            mm_kt(acc, Wcur, v1, 3);
        } else {
            half8 v0[4];
            rd_vf(vcur, 0, arow, ag, v0);
            mm_kt(acc, Wcur, v0, 0);
        }

        #pragma unroll
        for (int bt = 0; bt < 4; ++bt) {
            unsigned short h[4];
            #pragma unroll
            for (int q = 0; q < 4; ++q) {
                float vn = Pv[bt][0] * acc[bt][0][q] + Pv[bt][1] * acc[bt][1][q]
                         + Pv[bt][2] * acc[bt][2][q] + Pv[bt][3] * acc[bt][3][q];
                h[q] = f16_bits(vn);
            }
            int row = bt * 16 + arow;
            int byte = (row * 256 + (rt * 16 + ag * 4) * 2) ^ ((row & 7) << 4);
            u32x2 pk;
            pk[0] = (unsigned)h[0] | ((unsigned)h[1] << 16);
            pk[1] = (unsigned)h[2] | ((unsigned)h[3] << 16);
            *reinterpret_cast<u32x2*>(reinterpret_cast<char*>(vnxt) + byte) = pk;
        }
    } else {
        // inactive r-tile: new state there is exactly zero
        #pragma unroll
        for (int bt = 0; bt < 4; ++bt) {
            int row = bt * 16 + arow;
            int byte = (row * 256 + (rt * 16 + ag * 4) * 2) ^ ((row & 7) << 4);
            *reinterpret_cast<u32x2*>(reinterpret_cast<char*>(vnxt) + byte) =
                u32x2{0u, 0u};
        }
    }

    // lgkm-only barrier (verified replay-safe in R15): LDS ping-pong drained,
    // W vmem stream stays in flight.
    asm volatile("s_waitcnt lgkmcnt(0)\n\ts_barrier" ::: "memory");
}

// ---- main: 256 blocks x 512 thr (8 waves = 8 r-tiles). Block = 64 batches,
// 1 block/CU. Bond-schedule sparsity: pairs 0,1,2,28,29,30 run truncated.
__global__ __launch_bounds__(512, 2) void mps_mfma(
    const float* __restrict__ x, const float* __restrict__ wf,
    const float* __restrict__ wl, const u32x4* __restrict__ wpk,
    float* __restrict__ out)
{
    __shared__ unsigned short vh0[BT * 128];     // 16 KB ping
    __shared__ unsigned short vh1[BT * 128];     // 16 KB pong
    __shared__ float Pt[NPAIR * BT * 4];         // 31.75 KB pair multipliers
    const int tid = threadIdx.x;
    const int lane = tid & 63;
    const int rt = tid >> 6;
    const int bbase = blockIdx.x * BT;

    // prologue A: P[p][row][i12] = s * x_{2p,i1} * x_{2p+1,i2}
    for (int idx = tid; idx < NPAIR * BT; idx += 512) {
        int pp = idx >> 6, row = idx & 63;
        const float* xb = &x[(size_t)(bbase + row) * 128 + 2 + 4 * pp];
        float2 xa = *reinterpret_cast<const float2*>(xb);
        float2 xc = *reinterpret_cast<const float2*>(xb + 2);
        float n2a = fmaf(xa.x, xa.x, fmaf(xa.y, xa.y, 1e-30f));
        float n2b = fmaf(xc.x, xc.x, fmaf(xc.y, xc.y, 1e-30f));
        float s = g_scale(2 * pp) * rsqrtf(n2a) * g_scale(2 * pp + 1) * rsqrtf(n2b);
        Pt[idx * 4 + 0] = s * xa.x * xc.x;
        Pt[idx * 4 + 1] = s * xa.x * xc.y;
        Pt[idx * 4 + 2] = s * xa.y * xc.x;
        Pt[idx * 4 + 3] = s * xa.y * xc.y;
    }

    // prologue B: v0 (only l<2 nonzero), normalized by s_init = 8*rsqrt(|x_0|^2)
    const float wf00 = wf[0], wf01 = wf[1], wf10 = wf[2], wf11 = wf[3];
    for (int idx = tid; idx < BT * 128; idx += 512) {
        int row = idx >> 7, l = idx & 127;
        float val = 0.f;
        if (l < 2) {
            float x0 = x[(size_t)(bbase + row) * 128 + 0];
            float x1 = x[(size_t)(bbase + row) * 128 + 1];
            float n2 = fmaf(x0, x0, fmaf(x1, x1, 1e-30f));
            float si = 8.0f * rsqrtf(n2);
            val = si * ((l == 0) ? (wf00 * x0 + wf10 * x1) : (wf01 * x0 + wf11 * x1));
        }
        int byte = (row * 256 + l * 2) ^ ((row & 7) << 4);
        *reinterpret_cast<unsigned short*>(
            reinterpret_cast<char*>(vh0) + byte) = f16_bits(val);
    }
    __syncthreads();

    // W double-buffers (zero-init so inactive-pair pins never touch junk)
    u32x4 WA[16], WB[16];
    #pragma unroll
    for (int j = 0; j < 16; ++j) {
        WA[j] = u32x4{0u, 0u, 0u, 0u};
        WB[j] = u32x4{0u, 0u, 0u, 0u};
    }

    // preload pair 0 (ktn=1, active wave rt=0 only)
    if (rt < 1) {
        #pragma unroll
        for (int i12 = 0; i12 < 4; ++i12)
            WA[i12 * 4] = wpk[(((size_t)i12 * 8 + rt) * 4) * 64 + lane];
    }

    // pair sequence with bond-schedule activity:
    // p : 0    1    2    3..27  28   29   30
    // ktn: 1    1    1    4      4    1    1
    // nr : 1    2    8    8      2    1    1
    do_pair<1, 1>(0, 1, rt < 1, rt < 2, Pt, lane, rt, vh0, vh1, wpk, WA, WB);
    do_pair<1, 1>(1, 2, rt < 2, true,   Pt, lane, rt, vh1, vh0, wpk, WB, WA);
    do_pair<1, 4>(2, 3, true,   true,   Pt, lane, rt, vh0, vh1, wpk, WA, WB);
    for (int p = 3; p < 27; p += 2) {
        do_pair<4, 4>(p,     p + 1, true, true, Pt, lane, rt, vh1, vh0, wpk, WB, WA);
        do_pair<4, 4>(p + 1, p + 2, true, true, Pt, lane, rt, vh0, vh1, wpk, WA, WB);
    }
    do_pair<4, 4>(27, 28, true,   rt < 2, Pt, lane, rt, vh1, vh0, wpk, WB, WA);
    do_pair<4, 1>(28, 29, rt < 2, rt < 1, Pt, lane, rt, vh0, vh1, wpk, WA, WB);
    do_pair<1, 1>(29, 30, rt < 1, rt < 1, Pt, lane, rt, vh1, vh0, wpk, WB, WA);
    do_pair<1, 1>(30, 30, rt < 1, false,  Pt, lane, rt, vh0, vh1, wpk, WA, WB);

    // finale: recompute alpha from global x (same factors as applied in-chain)
    if (tid < BT) {
        int row = tid;
        const float* xb = &x[(size_t)(bbase + row) * 128];
        float n2i = fmaf(xb[0], xb[0], fmaf(xb[1], xb[1], 1e-30f));
        float alpha = 8.0f * rsqrtf(n2i);
        for (int k = 0; k < NMID; ++k) {
            float2 xx = *reinterpret_cast<const float2*>(&xb[2 + 2 * k]);
            float n2 = fmaf(xx.x, xx.x, fmaf(xx.y, xx.y, 1e-30f));
            alpha *= g_scale(k) * rsqrtf(n2);
        }
        int boff = (row * 256) ^ ((row & 7) << 4);
        unsigned hw = *reinterpret_cast<unsigned*>(
            reinterpret_cast<char*>(vh1) + boff);
        float v0 = (float)__builtin_bit_cast(_Float16, (unsigned short)(hw & 0xffffu));
        float v1 = (float)__builtin_bit_cast(_Float16, (unsigned short)(hw >> 16));
        float x0 = xb[126], x1 = xb[127];
        float val = v0 * (wl[0] * x0 + wl[1] * x1)
                  + v1 * (wl[2] * x0 + wl[3] * x1);
        out[bbase + row] = val / alpha;
    }
}

// ---------------- fallback fp32 vector kernel (used only if ws too small) ----
#define FBT 32
__global__ __launch_bounds__(256, 2) void mps_chain_kernel(
    const float* __restrict__ x, const float* __restrict__ wf,
    const float* __restrict__ wm, const float* __restrict__ wl,
    float* __restrict__ out)
{
    __shared__ float vbuf[2][128][FBT];
    __shared__ float xs_lds[FBT][126];
    const int tid = threadIdx.x;
    const int rg = tid >> 3, bg = tid & 7;
    const int r0 = rg * 4, b0 = bg * 4;
    const int bbase = blockIdx.x * FBT;
    for (int idx = tid; idx < FBT * 126; idx += 256) {
        int b = idx / 126, j = idx % 126;
        xs_lds[b][j] = x[(size_t)(bbase + b) * 128 + 2 + j];
    }
    const float wf00 = wf[0], wf01 = wf[1], wf10 = wf[2], wf11 = wf[3];
    for (int idx = tid; idx < 128 * FBT; idx += 256) {
        int l = idx / FBT, b = idx % FBT;
        float val = 0.0f;
        if (l < 2) {
            float x0 = x[(size_t)(bbase + b) * 128 + 0];
            float x1 = x[(size_t)(bbase + b) * 128 + 1];
            val = (l == 0) ? (wf00 * x0 + wf10 * x1) : (wf01 * x0 + wf11 * x1);
        }
        vbuf[0][l][b] = val;
    }
    __syncthreads();
    int cur = 0;
    for (int k = 0; k < NMID; ++k) {
        const float* __restrict__ Wk = wm + (size_t)k * (2 * 128 * 128);
        float acc0[4][4], acc1[4][4];
        #pragma unroll
        for (int bb = 0; bb < 4; ++bb)
            #pragma unroll
            for (int rr = 0; rr < 4; ++rr) { acc0[bb][rr] = 0.0f; acc1[bb][rr] = 0.0f; }
        #pragma unroll 4
        for (int l = 0; l < 128; ++l) {
            float4 vv = *reinterpret_cast<const float4*>(&vbuf[cur][l][b0]);
            float4 w0 = *reinterpret_cast<const float4*>(&Wk[(size_t)(2 * l) * 128 + r0]);
            float4 w1 = *reinterpret_cast<const float4*>(&Wk[(size_t)(2 * l + 1) * 128 + r0]);
            float va[4] = { vv.x, vv.y, vv.z, vv.w };
            float w0a[4] = { w0.x, w0.y, w0.z, w0.w };
            float w1a[4] = { w1.x, w1.y, w1.z, w1.w };
            #pragma unroll
            for (int bb = 0; bb < 4; ++bb)
                #pragma unroll
                for (int rr = 0; rr < 4; ++rr) {
                    acc0[bb][rr] = fmaf(va[bb], w0a[rr], acc0[bb][rr]);
                    acc1[bb][rr] = fmaf(va[bb], w1a[rr], acc1[bb][rr]);
                }
        }
        const int nxt = cur ^ 1;
        float vn[4][4];
        #pragma unroll
        for (int bb = 0; bb < 4; ++bb) {
            float xx0 = xs_lds[b0 + bb][2 * k + 0];
            float xx1 = xs_lds[b0 + bb][2 * k + 1];
            #pragma unroll
            for (int rr = 0; rr < 4; ++rr)
                vn[bb][rr] = xx0 * acc0[bb][rr] + xx1 * acc1[bb][rr];
        }
        #pragma unroll
        for (int rr = 0; rr < 4; ++rr) {
            float4 wv = make_float4(vn[0][rr], vn[1][rr], vn[2][rr], vn[3][rr]);
            *reinterpret_cast<float4*>(&vbuf[nxt][r0 + rr][b0]) = wv;
        }
        cur = nxt;
        __syncthreads();
    }
    if (rg == 0) {
        const float wl00 = wl[0], wl01 = wl[1], wl10 = wl[2], wl11 = wl[3];
        #pragma unroll
        for (int bb = 0; bb < 4; ++bb) {
            int b = b0 + bb;
            float v0 = vbuf[cur][0][b];
            float v1 = vbuf[cur][1][b];
            float xx0 = xs_lds[b][124];
            float xx1 = xs_lds[b][125];
            out[bbase + b] = v0 * (wl00 * xx0 + wl01 * xx1)
                           + v1 * (wl10 * xx0 + wl11 * xx1);
        }
    }
}

extern "C" void kernel_launch(void* const* d_in, const int* in_sizes, int n_in,
                              void* d_out, int out_size, void* d_ws, size_t ws_size,
                              hipStream_t stream) {
    const float* x  = (const float*)d_in[0];
    const float* wf = (const float*)d_in[1];
    const float* wm = (const float*)d_in[2];
    const float* wl = (const float*)d_in[3];
    float* out = (float*)d_out;

    const size_t ws_needed = (size_t)NPAIR * 4 * 8 * 4 * 64 * 16;  // 4.06 MB packed W2
    if (ws_size >= ws_needed) {
        hipLaunchKernelGGL(mps_pack_w2, dim3(NPAIR * 4 * 8), dim3(256), 0, stream,
                           wm, (unsigned*)d_ws);
        hipLaunchKernelGGL(mps_mfma, dim3(NBATCH / BT), dim3(512), 0, stream,
                           x, wf, wl, (const u32x4*)d_ws, out);
    } else {
        hipLaunchKernelGGL(mps_chain_kernel, dim3(NBATCH / FBT), dim3(256), 0, stream,
                           x, wf, wm, wl, out);
    }
}